// Round 3
// baseline (456.502 us; speedup 1.0000x reference)
//
#include <hip/hip_runtime.h>
#include <hip/hip_bf16.h>

#define MIDF 256
#define OUTF 64
#define CF 64
#define TWO_C 128
#define BN_EPS 1e-5f
#define BCAP 1024    // per-64-node-bucket capacity (mean 819, +7 sigma margin)
#define NBMAX 1600
#define AGG_LD 136   // LDS agg tile row stride (bf16): 128 + 8 pad
#define OB_LD 264    // LDS h tile row stride (bf16): 256 + 8 pad (k_back)

typedef __attribute__((ext_vector_type(8))) short bf16x8;
typedef __attribute__((ext_vector_type(4))) float f32x4;

__device__ __forceinline__ ushort f2bf(float f) {
  union { float f; unsigned u; } v; v.f = f;
  return (ushort)((v.u + 0x7fffu + ((v.u >> 16) & 1u)) >> 16);
}
__device__ __forceinline__ float bf2f(unsigned u16) {
  union { unsigned u; float f; } v; v.u = u16 << 16;
  return v.f;
}

// ---------------- init bucket cursors + bnacc (4 spread copies) ----------------
__global__ __launch_bounds__(1024) void k_init(int* __restrict__ gcur,
                                               float* __restrict__ bnacc, int NB) {
  int i = threadIdx.x;
  for (; i < NB; i += 1024) gcur[i] = i * BCAP;
  for (i = threadIdx.x; i < 2048; i += 1024) bnacc[i] = 0.f;
}

// ---------------- fused front end: bucket scatter + x cast + W1 transpose-cast ----------------
__global__ __launch_bounds__(1024) void k_front(const int* __restrict__ ei,
    const float* __restrict__ ea, int* __restrict__ gcur, uint2* __restrict__ ebt,
    int E, int NB, int nchunks,
    const float4* __restrict__ xp, uint4* __restrict__ xb, int n8,
    const float* __restrict__ W1, ushort* __restrict__ W1t) {
  __shared__ int lh[NBMAX];
  __shared__ int lb[NBMAX];
  int tid = threadIdx.x;
  if ((int)blockIdx.x == (int)gridDim.x - 1) {
    // ---- W1 [128][256] f32 -> W1t [256][128] bf16 (B-frag friendly layout) ----
    for (int i = tid; i < TWO_C * MIDF; i += 1024) {
      int c = i & (MIDF - 1), k = i >> 8;
      W1t[(size_t)c * TWO_C + k] = f2bf(W1[(size_t)k * MIDF + c]);
    }
    return;
  }
  if ((int)blockIdx.x >= nchunks) {
    // ---- x -> bf16 cast path ----
    int nb2 = gridDim.x - 1 - nchunks;
    int i = ((int)blockIdx.x - nchunks) * 1024 + tid;
    int st = nb2 * 1024;
    for (; i < n8; i += st) {
      float4 a = xp[2 * i], b = xp[2 * i + 1];
      uint4 o;
      o.x = (unsigned)f2bf(a.x) | ((unsigned)f2bf(a.y) << 16);
      o.y = (unsigned)f2bf(a.z) | ((unsigned)f2bf(a.w) << 16);
      o.z = (unsigned)f2bf(b.x) | ((unsigned)f2bf(b.y) << 16);
      o.w = (unsigned)f2bf(b.z) | ((unsigned)f2bf(b.w) << 16);
      xb[i] = o;
    }
    return;
  }
  // ---- bucket scatter path: 4096-edge chunk, 16 waves ----
  int c0 = blockIdx.x * 4096;
  for (int b = tid; b < NB; b += 1024) lh[b] = 0;
  __syncthreads();
  int rows[4];
#pragma unroll
  for (int j = 0; j < 4; ++j) {
    int e = c0 + j * 1024 + tid;
    int r = (e < E) ? ei[e] : -1;
    rows[j] = r;
    if (r >= 0) atomicAdd(&lh[r >> 6], 1);
  }
  __syncthreads();
  for (int b = tid; b < NB; b += 1024) {
    int c = lh[b];
    lb[b] = (c > 0) ? atomicAdd(&gcur[b], c) : 0;
  }
  __syncthreads();
#pragma unroll
  for (int j = 0; j < 4; ++j) {
    int r = rows[j];
    if (r >= 0) {
      int e = c0 + j * 1024 + tid;
      int pos = atomicAdd(&lb[r >> 6], 1);
      ebt[pos] = make_uint2((unsigned)ei[E + e] | ((unsigned)(r & 63) << 20),
                            __float_as_uint(ea[e]));
    }
  }
}

// ---- fused: bucket sort + segmented mean + GEMM1 (BN stats only, in-register) + agg store ----
__global__ __launch_bounds__(512, 8) void k_fused(const ushort* __restrict__ xb,
    const uint2* __restrict__ ebt, const int* __restrict__ gcur,
    const ushort* __restrict__ W1t, const float* __restrict__ b1,
    ushort* __restrict__ agg, float* __restrict__ bnacc, int n, int NB) {
  __shared__ uint2 recs[BCAP];              // 8192 B sorted records
  __shared__ ushort aggT[64 * AGG_LD];      // 17408 B agg tile (MFMA A operand)
  __shared__ int hist[64], cbase[64], cursor[64];   // total LDS ~26.4 KB -> 4 blocks/CU
  int tid = threadIdx.x;
  int w = tid >> 6, lane = tid & 63;
  int q = lane >> 4, l16 = lane & 15;
  // preload this wave's W1 B-fragments (cols [w*32, w*32+32)) + bias
  bf16x8 Bf[2][4];
  float bias[2];
#pragma unroll
  for (int c2 = 0; c2 < 2; ++c2) {
    int col = w * 32 + c2 * 16 + l16;
#pragma unroll
    for (int ks = 0; ks < 4; ++ks)
      Bf[c2][ks] = *(const bf16x8*)(W1t + (size_t)col * TWO_C + ks * 32 + q * 8);
    bias[c2] = b1[col];
  }
  float bs0 = 0.f, bs1 = 0.f, bq0 = 0.f, bq1 = 0.f;   // BN accumulators (2 cols/lane)
  for (int b = blockIdx.x; b < NB; b += gridDim.x) {
    int base = b * BCAP;
    int r0 = b << 6;
    int cnt = gcur[b] - base;
    cnt = min(cnt, BCAP);
    if (tid < 64) hist[tid] = 0;
    __syncthreads();
    // single global read of ebt into registers
    uint2 e0 = make_uint2(0u, 0u), e1 = make_uint2(0u, 0u);
    bool v0 = tid < cnt, v1 = 512 + tid < cnt;
    if (v0) e0 = ebt[base + tid];
    if (v1) e1 = ebt[base + 512 + tid];
    if (v0) atomicAdd(&hist[(e0.x >> 20) & 63], 1);
    if (v1) atomicAdd(&hist[(e1.x >> 20) & 63], 1);
    __syncthreads();
    if (tid < 64) {                      // wave 0: 64-wide inclusive scan
      int v = hist[tid];
      int sc = v;
#pragma unroll
      for (int d = 1; d < 64; d <<= 1) {
        int t = __shfl_up(sc, d);
        if (tid >= d) sc += t;
      }
      cbase[tid] = sc - v;
      cursor[tid] = sc - v;
    }
    __syncthreads();
    if (v0) {
      int pos = atomicAdd(&cursor[(e0.x >> 20) & 63], 1);
      recs[pos] = make_uint2(e0.x & 0xFFFFF, e0.y);
    }
    if (v1) {
      int pos = atomicAdd(&cursor[(e1.x >> 20) & 63], 1);
      recs[pos] = make_uint2(e1.x & 0xFFFFF, e1.y);
    }
    __syncthreads();
    // segmented mean -> aggT (bf16, rows always written; empty/tail rows = 0)
#pragma unroll
    for (int j = 0; j < 8; ++j) {
      int rl = w * 8 + j;
      int s = cbase[rl], d = hist[rl];
      int e = s + d;
      float s0 = 0.f, s1 = 0.f, s2 = 0.f, s3 = 0.f;
      float t0 = 0.f, t1 = 0.f, t2 = 0.f, t3 = 0.f;
      int i = s + q;
      for (; i + 4 < e; i += 8) {
        uint2 pa = recs[i], pb = recs[i + 4];
        uint2 xa = *(const uint2*)(xb + (size_t)pa.x * CF + 4 * l16);
        uint2 xc = *(const uint2*)(xb + (size_t)pb.x * CF + 4 * l16);
        float wa = __uint_as_float(pa.y), wb = __uint_as_float(pb.y);
        float a0 = bf2f(xa.x & 0xffff), a1 = bf2f(xa.x >> 16);
        float a2 = bf2f(xa.y & 0xffff), a3 = bf2f(xa.y >> 16);
        float b0 = bf2f(xc.x & 0xffff), b1v = bf2f(xc.x >> 16);
        float b2v = bf2f(xc.y & 0xffff), b3 = bf2f(xc.y >> 16);
        s0 += a0 + b0; s1 += a1 + b1v; s2 += a2 + b2v; s3 += a3 + b3;
        t0 += a0 * wa + b0 * wb; t1 += a1 * wa + b1v * wb;
        t2 += a2 * wa + b2v * wb; t3 += a3 * wa + b3 * wb;
      }
      if (i < e) {
        uint2 p = recs[i];
        uint2 xv = *(const uint2*)(xb + (size_t)p.x * CF + 4 * l16);
        float wt = __uint_as_float(p.y);
        float a0 = bf2f(xv.x & 0xffff), a1 = bf2f(xv.x >> 16);
        float a2 = bf2f(xv.y & 0xffff), a3 = bf2f(xv.y >> 16);
        s0 += a0; s1 += a1; s2 += a2; s3 += a3;
        t0 += a0 * wt; t1 += a1 * wt; t2 += a2 * wt; t3 += a3 * wt;
      }
      s0 += __shfl_xor(s0, 16); s1 += __shfl_xor(s1, 16);
      s2 += __shfl_xor(s2, 16); s3 += __shfl_xor(s3, 16);
      t0 += __shfl_xor(t0, 16); t1 += __shfl_xor(t1, 16);
      t2 += __shfl_xor(t2, 16); t3 += __shfl_xor(t3, 16);
      s0 += __shfl_xor(s0, 32); s1 += __shfl_xor(s1, 32);
      s2 += __shfl_xor(s2, 32); s3 += __shfl_xor(s3, 32);
      t0 += __shfl_xor(t0, 32); t1 += __shfl_xor(t1, 32);
      t2 += __shfl_xor(t2, 32); t3 += __shfl_xor(t3, 32);
      float inv = 1.0f / fmaxf((float)d, 1.0f);
      if (q == 0) {
        uint2 o;
        o.x = (unsigned)f2bf(s0 * inv) | ((unsigned)f2bf(s1 * inv) << 16);
        o.y = (unsigned)f2bf(s2 * inv) | ((unsigned)f2bf(s3 * inv) << 16);
        *(uint2*)(aggT + rl * AGG_LD + 4 * l16) = o;
        uint2 p2;
        p2.x = (unsigned)f2bf(t0 * inv) | ((unsigned)f2bf(t1 * inv) << 16);
        p2.y = (unsigned)f2bf(t2 * inv) | ((unsigned)f2bf(t3 * inv) << 16);
        *(uint2*)(aggT + rl * AGG_LD + CF + 4 * l16) = p2;
      }
    }
    __syncthreads();
    // agg global store from LDS (64 rows x 128 bf16, coalesced 32B/thread)
    {
      int row = tid >> 3, seg = tid & 7;
      int gr = r0 + row;
      if (gr < n) {
        const uint4* src = (const uint4*)(aggT + row * AGG_LD + seg * 16);
        uint4* dst = (uint4*)(agg + (size_t)gr * TWO_C + seg * 16);
        dst[0] = src[0];
        dst[1] = src[1];
      }
    }
    // MFMA GEMM1 (for BN stats only; h recomputed later in k_back)
    f32x4 acc[4][2];
#pragma unroll
    for (int rt = 0; rt < 4; ++rt)
#pragma unroll
      for (int c2 = 0; c2 < 2; ++c2) acc[rt][c2] = (f32x4){0.f, 0.f, 0.f, 0.f};
#pragma unroll
    for (int rt = 0; rt < 4; ++rt) {
      bf16x8 Af[4];
#pragma unroll
      for (int ks = 0; ks < 4; ++ks)
        Af[ks] = *(const bf16x8*)(aggT + (size_t)(rt * 16 + l16) * AGG_LD + ks * 32 + q * 8);
#pragma unroll
      for (int ks = 0; ks < 4; ++ks)
#pragma unroll
        for (int c2 = 0; c2 < 2; ++c2)
          acc[rt][c2] = __builtin_amdgcn_mfma_f32_16x16x32_bf16(Af[ks], Bf[c2][ks], acc[rt][c2], 0, 0, 0);
    }
    // BN stats straight from accumulator registers
#pragma unroll
    for (int rt = 0; rt < 4; ++rt)
#pragma unroll
      for (int r = 0; r < 4; ++r) {
        int grow = r0 + rt * 16 + q * 4 + r;
        if (grow < n) {
          float v0c = fmaxf(acc[rt][0][r] + bias[0], 0.f);
          float v1c = fmaxf(acc[rt][1][r] + bias[1], 0.f);
          bs0 += v0c; bq0 += v0c * v0c;
          bs1 += v1c; bq1 += v1c * v1c;
        }
      }
  }
  // reduce BN accumulators over the 4 q-groups, then global atomics (4-way spread)
  bs0 += __shfl_xor(bs0, 16); bs0 += __shfl_xor(bs0, 32);
  bq0 += __shfl_xor(bq0, 16); bq0 += __shfl_xor(bq0, 32);
  bs1 += __shfl_xor(bs1, 16); bs1 += __shfl_xor(bs1, 32);
  bq1 += __shfl_xor(bq1, 16); bq1 += __shfl_xor(bq1, 32);
  if (q == 0) {
    int cpy = ((int)blockIdx.x & 3) * 512;
    int col0 = w * 32 + l16, col1 = w * 32 + 16 + l16;
    atomicAdd(&bnacc[cpy + col0], bs0);
    atomicAdd(&bnacc[cpy + 256 + col0], bq0);
    atomicAdd(&bnacc[cpy + col1], bs1);
    atomicAdd(&bnacc[cpy + 256 + col1], bq1);
  }
}

// ---------------- finalize BN + fold into W2 (bf16 transposed) / b2 ----------------
__global__ __launch_bounds__(256) void k_final(const float* __restrict__ bnacc,
    const float* __restrict__ gamma, const float* __restrict__ beta,
    const float* __restrict__ W2, const float* __restrict__ b2,
    ushort* __restrict__ W2pt, float* __restrict__ b2p, float invN) {
  __shared__ float scb[MIDF], shb[MIDF], red[256];
  int tid = threadIdx.x;
  float s = bnacc[tid] + bnacc[512 + tid] + bnacc[1024 + tid] + bnacc[1536 + tid];
  float qv = bnacc[256 + tid] + bnacc[768 + tid] + bnacc[1280 + tid] + bnacc[1792 + tid];
  float mu = s * invN;
  float var = qv * invN - mu * mu;
  float sc = gamma[tid] * rsqrtf(var + BN_EPS);
  scb[tid] = sc;
  shb[tid] = beta[tid] - mu * sc;
  __syncthreads();
  float sp = 0.f;
  for (int i = tid; i < MIDF * OUTF; i += 256) {
    int k = i >> 6, c = i & 63;
    float wv = W2[i];
    W2pt[(size_t)c * MIDF + k] = f2bf(scb[k] * wv);   // [64 col][256 k] bf16
    sp += shb[k] * wv;
  }
  red[tid] = sp;
  __syncthreads();
  if (tid < 64)
    b2p[tid] = b2[tid] + red[tid] + red[64 + tid] + red[128 + tid] + red[192 + tid];
}

// ---- back end: recompute h=relu(agg@W1+b1) per tile (LDS), then @W2pt+b2p -> out ----
__global__ __launch_bounds__(256, 4) void k_back(const ushort* __restrict__ agg,
    const ushort* __restrict__ W1t, const float* __restrict__ b1,
    const ushort* __restrict__ W2pt, const float* __restrict__ b2p,
    float* __restrict__ out, int n, int ntiles) {
  __shared__ ushort hT[64 * OB_LD];     // 33792 B -> 4 blocks/CU
  int tid = threadIdx.x, w = tid >> 6, lane = tid & 63;
  int q = lane >> 4, l16 = lane & 15;
  float bias1[4], b2b[4];
#pragma unroll
  for (int ct = 0; ct < 4; ++ct) {
    bias1[ct] = b1[w * 64 + ct * 16 + l16];
    b2b[ct] = b2p[ct * 16 + l16];
  }
  for (int t = blockIdx.x; t < ntiles; t += gridDim.x) {
    int r0 = t * 64;
    // ---- stage 1: wave w recomputes h cols [w*64, w*64+64) for all 64 rows ----
    bf16x8 Af[4][4];
#pragma unroll
    for (int rt = 0; rt < 4; ++rt) {
      int row = r0 + rt * 16 + l16;
      bool ok = row < n;
#pragma unroll
      for (int ks = 0; ks < 4; ++ks) {
        bf16x8 v;
#pragma unroll
        for (int j = 0; j < 8; ++j) v[j] = 0;
        if (ok) v = *(const bf16x8*)(agg + (size_t)row * TWO_C + ks * 32 + q * 8);
        Af[rt][ks] = v;
      }
    }
#pragma unroll
    for (int ct = 0; ct < 4; ++ct) {
      f32x4 acc1[4];
#pragma unroll
      for (int rt = 0; rt < 4; ++rt) acc1[rt] = (f32x4){0.f, 0.f, 0.f, 0.f};
#pragma unroll
      for (int ks = 0; ks < 4; ++ks) {
        bf16x8 Bv = *(const bf16x8*)(W1t + (size_t)(w * 64 + ct * 16 + l16) * TWO_C + ks * 32 + q * 8);
#pragma unroll
        for (int rt = 0; rt < 4; ++rt)
          acc1[rt] = __builtin_amdgcn_mfma_f32_16x16x32_bf16(Af[rt][ks], Bv, acc1[rt], 0, 0, 0);
      }
#pragma unroll
      for (int rt = 0; rt < 4; ++rt)
#pragma unroll
        for (int r = 0; r < 4; ++r)
          hT[(rt * 16 + q * 4 + r) * OB_LD + w * 64 + ct * 16 + l16] =
              f2bf(fmaxf(acc1[rt][r] + bias1[ct], 0.f));
    }
    __syncthreads();
    // ---- stage 2: wave w computes out rows [w*16, w*16+16) = hT @ W2pt + b2p ----
    f32x4 acc2[4];
#pragma unroll
    for (int ct = 0; ct < 4; ++ct) acc2[ct] = (f32x4){0.f, 0.f, 0.f, 0.f};
#pragma unroll
    for (int ks = 0; ks < 8; ++ks) {
      bf16x8 A2 = *(const bf16x8*)(hT + (size_t)(w * 16 + l16) * OB_LD + ks * 32 + q * 8);
#pragma unroll
      for (int ct = 0; ct < 4; ++ct) {
        bf16x8 Bv = *(const bf16x8*)(W2pt + (size_t)(ct * 16 + l16) * MIDF + ks * 32 + q * 8);
        acc2[ct] = __builtin_amdgcn_mfma_f32_16x16x32_bf16(A2, Bv, acc2[ct], 0, 0, 0);
      }
    }
#pragma unroll
    for (int ct = 0; ct < 4; ++ct)
#pragma unroll
      for (int r = 0; r < 4; ++r) {
        int gr = r0 + w * 16 + q * 4 + r;
        if (gr < n) out[(size_t)gr * OUTF + ct * 16 + l16] = acc2[ct][r] + b2b[ct];
      }
    __syncthreads();
  }
}

extern "C" void kernel_launch(void* const* d_in, const int* in_sizes, int n_in,
                              void* d_out, int out_size, void* d_ws, size_t ws_size,
                              hipStream_t stream) {
  const float* x     = (const float*)d_in[0];
  const int*   ei    = (const int*)d_in[1];
  const float* ea    = (const float*)d_in[2];
  const float* W1    = (const float*)d_in[4];
  const float* b1    = (const float*)d_in[5];
  const float* gamma = (const float*)d_in[6];
  const float* beta  = (const float*)d_in[7];
  const float* W2    = (const float*)d_in[8];
  const float* b2    = (const float*)d_in[9];
  float* out = (float*)d_out;
  int E = in_sizes[2];
  int n = in_sizes[3];
  int NB = (n + 63) >> 6;               // 64-node buckets (1563 for n=100000)

  // workspace layout (h eliminated — agg stored instead, ~52 MB total)
  char* ws = (char*)d_ws;
  ushort* agg  = (ushort*)ws;                          // n*128 bf16 (25.6 MB)
  ushort* xb   = agg + (size_t)n * TWO_C;              // n*64 bf16 (12.8 MB)
  uint2* ebt   = (uint2*)(xb + (size_t)n * CF);        // NBMAX*BCAP recs (13.1 MB)
  ushort* W1t  = (ushort*)(ebt + (size_t)NBMAX * BCAP);// 32768 bf16 (64 KB)
  ushort* W2pt = W1t + TWO_C * MIDF;                   // 16384 bf16 (32 KB)
  float* b2p   = (float*)(W2pt + MIDF * OUTF);         // 64 f32
  int* gcur    = (int*)(b2p + 64);                     // NBMAX int
  float* bnacc = (float*)(gcur + NBMAX);               // 2048 f32 (4 spread copies)

  int nchunks = (E + 4095) / 4096;
  hipLaunchKernelGGL(k_init, dim3(1), dim3(1024), 0, stream, gcur, bnacc, NB);
  hipLaunchKernelGGL(k_front, dim3(nchunks + 257), dim3(1024), 0, stream,
                     ei, ea, gcur, ebt, E, NB, nchunks,
                     (const float4*)x, (uint4*)xb, n * CF / 8, W1, W1t);
  hipLaunchKernelGGL(k_fused, dim3(1024), dim3(512), 0, stream,
                     xb, ebt, gcur, W1t, b1, agg, bnacc, n, NB);
  hipLaunchKernelGGL(k_final, dim3(1), dim3(256), 0, stream, bnacc, gamma, beta,
                     W2, b2, W2pt, b2p, 1.0f / (float)n);
  int nt = (n + 63) / 64;
  hipLaunchKernelGGL(k_back, dim3(1024), dim3(256), 0, stream,
                     agg, W1t, b1, W2pt, b2p, out, n, nt);
}

// Round 4
// 263.269 us; speedup vs baseline: 1.7340x; 1.7340x over previous
//
#include <hip/hip_runtime.h>
#include <hip/hip_bf16.h>

#define MIDF 256
#define OUTF 64
#define CF 64
#define TWO_C 128
#define BN_EPS 1e-5f
#define BCAP 1024    // per-64-node-bucket capacity (mean 819, +7 sigma margin)
#define NBMAX 1600
#define HT_LD 264    // LDS h tile row stride (bf16): 256 + 8 pad (k_back)

typedef __attribute__((ext_vector_type(8))) short bf16x8;
typedef __attribute__((ext_vector_type(4))) float f32x4;

__device__ __forceinline__ ushort f2bf(float f) {
  union { float f; unsigned u; } v; v.f = f;
  return (ushort)((v.u + 0x7fffu + ((v.u >> 16) & 1u)) >> 16);
}
__device__ __forceinline__ float bf2f(unsigned u16) {
  union { unsigned u; float f; } v; v.u = u16 << 16;
  return v.f;
}

// ---------------- init bucket cursors + bnacc (4 spread copies) ----------------
__global__ __launch_bounds__(1024) void k_init(int* __restrict__ gcur,
                                               float* __restrict__ bnacc, int NB) {
  int i = threadIdx.x;
  for (; i < NB; i += 1024) gcur[i] = i * BCAP;
  for (i = threadIdx.x; i < 2048; i += 1024) bnacc[i] = 0.f;
}

// ---------------- fused front end: bucket scatter + x cast + W1 transpose-cast ----------------
__global__ __launch_bounds__(1024) void k_front(const int* __restrict__ ei,
    const float* __restrict__ ea, int* __restrict__ gcur, uint2* __restrict__ ebt,
    int E, int NB, int nchunks,
    const float4* __restrict__ xp, uint4* __restrict__ xb, int n8,
    const float* __restrict__ W1, ushort* __restrict__ W1t) {
  __shared__ int lh[NBMAX];
  __shared__ int lb[NBMAX];
  int tid = threadIdx.x;
  if ((int)blockIdx.x == (int)gridDim.x - 1) {
    // ---- W1 [128][256] f32 -> W1t [256][128] bf16 (B-frag friendly layout) ----
    for (int i = tid; i < TWO_C * MIDF; i += 1024) {
      int c = i & (MIDF - 1), k = i >> 8;
      W1t[(size_t)c * TWO_C + k] = f2bf(W1[(size_t)k * MIDF + c]);
    }
    return;
  }
  if ((int)blockIdx.x >= nchunks) {
    // ---- x -> bf16 cast path ----
    int nb2 = gridDim.x - 1 - nchunks;
    int i = ((int)blockIdx.x - nchunks) * 1024 + tid;
    int st = nb2 * 1024;
    for (; i < n8; i += st) {
      float4 a = xp[2 * i], b = xp[2 * i + 1];
      uint4 o;
      o.x = (unsigned)f2bf(a.x) | ((unsigned)f2bf(a.y) << 16);
      o.y = (unsigned)f2bf(a.z) | ((unsigned)f2bf(a.w) << 16);
      o.z = (unsigned)f2bf(b.x) | ((unsigned)f2bf(b.y) << 16);
      o.w = (unsigned)f2bf(b.z) | ((unsigned)f2bf(b.w) << 16);
      xb[i] = o;
    }
    return;
  }
  // ---- bucket scatter path: 4096-edge chunk, 16 waves ----
  int c0 = blockIdx.x * 4096;
  for (int b = tid; b < NB; b += 1024) lh[b] = 0;
  __syncthreads();
  int rows[4];
#pragma unroll
  for (int j = 0; j < 4; ++j) {
    int e = c0 + j * 1024 + tid;
    int r = (e < E) ? ei[e] : -1;
    rows[j] = r;
    if (r >= 0) atomicAdd(&lh[r >> 6], 1);
  }
  __syncthreads();
  for (int b = tid; b < NB; b += 1024) {
    int c = lh[b];
    lb[b] = (c > 0) ? atomicAdd(&gcur[b], c) : 0;
  }
  __syncthreads();
#pragma unroll
  for (int j = 0; j < 4; ++j) {
    int r = rows[j];
    if (r >= 0) {
      int e = c0 + j * 1024 + tid;
      int pos = atomicAdd(&lb[r >> 6], 1);
      ebt[pos] = make_uint2((unsigned)ei[E + e] | ((unsigned)(r & 63) << 20),
                            __float_as_uint(ea[e]));
    }
  }
}

// ---------------- bucket sort (to LDS) + segmented mean -> agg (round-0 proven) ----------------
__global__ __launch_bounds__(512, 4) void k_sortagg(const ushort* __restrict__ xb,
    const uint2* __restrict__ ebt, const int* __restrict__ gcur,
    ushort* __restrict__ agg, int n) {
  __shared__ uint2 recs[BCAP];        // 8 KB sorted records
  __shared__ int hist[64], cbase[64], cursor[64];
  int tid = threadIdx.x;
  int b = blockIdx.x;
  int base = b * BCAP;
  int cnt = gcur[b] - base;
  if (tid < 64) hist[tid] = 0;
  __syncthreads();
  for (int i = tid; i < cnt; i += 512)
    atomicAdd(&hist[(ebt[base + i].x >> 20) & 63], 1);
  __syncthreads();
  if (tid < 64) {                      // wave 0: 64-wide inclusive scan
    int v = hist[tid];
    int sc = v;
#pragma unroll
    for (int d = 1; d < 64; d <<= 1) {
      int t = __shfl_up(sc, d);
      if (tid >= d) sc += t;
    }
    cbase[tid] = sc - v;
    cursor[tid] = sc - v;
  }
  __syncthreads();
  for (int i = tid; i < cnt; i += 512) {
    uint2 rec = ebt[base + i];
    int pos = atomicAdd(&cursor[(rec.x >> 20) & 63], 1);
    recs[pos] = make_uint2(rec.x & 0xFFFFF, rec.y);
  }
  __syncthreads();
  int w = tid >> 6, lane = tid & 63;
  int q4 = lane >> 4, l16 = lane & 15;
#pragma unroll
  for (int j = 0; j < 8; ++j) {
    int rl = w * 8 + j;
    int v = (b << 6) + rl;
    if (v >= n) continue;
    int s = cbase[rl], d = hist[rl];
    int e = s + d;
    float s0 = 0.f, s1 = 0.f, s2 = 0.f, s3 = 0.f;
    float t0 = 0.f, t1 = 0.f, t2 = 0.f, t3 = 0.f;
    int i = s + q4;
    for (; i + 4 < e; i += 8) {
      uint2 pa = recs[i], pb = recs[i + 4];
      uint2 xa = *(const uint2*)(xb + (size_t)pa.x * CF + 4 * l16);
      uint2 xc = *(const uint2*)(xb + (size_t)pb.x * CF + 4 * l16);
      float wa = __uint_as_float(pa.y), wb = __uint_as_float(pb.y);
      float a0 = bf2f(xa.x & 0xffff), a1 = bf2f(xa.x >> 16);
      float a2 = bf2f(xa.y & 0xffff), a3 = bf2f(xa.y >> 16);
      float b0 = bf2f(xc.x & 0xffff), b1 = bf2f(xc.x >> 16);
      float b2 = bf2f(xc.y & 0xffff), b3 = bf2f(xc.y >> 16);
      s0 += a0 + b0; s1 += a1 + b1; s2 += a2 + b2; s3 += a3 + b3;
      t0 += a0 * wa + b0 * wb; t1 += a1 * wa + b1 * wb;
      t2 += a2 * wa + b2 * wb; t3 += a3 * wa + b3 * wb;
    }
    if (i < e) {
      uint2 p = recs[i];
      uint2 xv = *(const uint2*)(xb + (size_t)p.x * CF + 4 * l16);
      float wt = __uint_as_float(p.y);
      float a0 = bf2f(xv.x & 0xffff), a1 = bf2f(xv.x >> 16);
      float a2 = bf2f(xv.y & 0xffff), a3 = bf2f(xv.y >> 16);
      s0 += a0; s1 += a1; s2 += a2; s3 += a3;
      t0 += a0 * wt; t1 += a1 * wt; t2 += a2 * wt; t3 += a3 * wt;
    }
    s0 += __shfl_xor(s0, 16); s1 += __shfl_xor(s1, 16);
    s2 += __shfl_xor(s2, 16); s3 += __shfl_xor(s3, 16);
    t0 += __shfl_xor(t0, 16); t1 += __shfl_xor(t1, 16);
    t2 += __shfl_xor(t2, 16); t3 += __shfl_xor(t3, 16);
    s0 += __shfl_xor(s0, 32); s1 += __shfl_xor(s1, 32);
    s2 += __shfl_xor(s2, 32); s3 += __shfl_xor(s3, 32);
    t0 += __shfl_xor(t0, 32); t1 += __shfl_xor(t1, 32);
    t2 += __shfl_xor(t2, 32); t3 += __shfl_xor(t3, 32);
    float inv = 1.0f / fmaxf((float)d, 1.0f);
    if (q4 == 0) {
      uint2 o;
      o.x = (unsigned)f2bf(s0 * inv) | ((unsigned)f2bf(s1 * inv) << 16);
      o.y = (unsigned)f2bf(s2 * inv) | ((unsigned)f2bf(s3 * inv) << 16);
      *(uint2*)(agg + (size_t)v * TWO_C + 4 * l16) = o;
      uint2 p2;
      p2.x = (unsigned)f2bf(t0 * inv) | ((unsigned)f2bf(t1 * inv) << 16);
      p2.y = (unsigned)f2bf(t2 * inv) | ((unsigned)f2bf(t3 * inv) << 16);
      *(uint2*)(agg + (size_t)v * TWO_C + CF + 4 * l16) = p2;
    }
  }
}

// ---------------- GEMM1 stats-only: BN sums from MFMA accumulators, no h write ----------------
__global__ __launch_bounds__(256, 4) void k_stats(const ushort* __restrict__ agg,
    const ushort* __restrict__ W1t, const float* __restrict__ b1,
    float* __restrict__ bnacc, int n, int ntiles) {
  int tid = threadIdx.x, w = tid >> 6, lane = tid & 63;
  int q = lane >> 4, l16 = lane & 15;
  int colbase = w * 64;
  bf16x8 Bf[4][4];
  float bias[4];
#pragma unroll
  for (int ct = 0; ct < 4; ++ct) {
    int col = colbase + ct * 16 + l16;
#pragma unroll
    for (int ks = 0; ks < 4; ++ks)
      Bf[ct][ks] = *(const bf16x8*)(W1t + (size_t)col * TWO_C + ks * 32 + q * 8);
    bias[ct] = b1[col];
  }
  float bs[4] = {0.f, 0.f, 0.f, 0.f}, bq[4] = {0.f, 0.f, 0.f, 0.f};
  for (int t = blockIdx.x; t < ntiles; t += gridDim.x) {
    int r0 = t * 64;
#pragma unroll
    for (int rt = 0; rt < 4; ++rt) {
      int row = r0 + rt * 16 + l16;
      bool ok = row < n;
      bf16x8 Af[4];
#pragma unroll
      for (int ks = 0; ks < 4; ++ks) {
        bf16x8 v;
#pragma unroll
        for (int j = 0; j < 8; ++j) v[j] = 0;
        if (ok) v = *(const bf16x8*)(agg + (size_t)row * TWO_C + ks * 32 + q * 8);
        Af[ks] = v;
      }
      f32x4 acc[4];
#pragma unroll
      for (int ct = 0; ct < 4; ++ct) acc[ct] = (f32x4){0.f, 0.f, 0.f, 0.f};
#pragma unroll
      for (int ks = 0; ks < 4; ++ks)
#pragma unroll
        for (int ct = 0; ct < 4; ++ct)
          acc[ct] = __builtin_amdgcn_mfma_f32_16x16x32_bf16(Af[ks], Bf[ct][ks], acc[ct], 0, 0, 0);
#pragma unroll
      for (int ct = 0; ct < 4; ++ct)
#pragma unroll
        for (int r = 0; r < 4; ++r) {
          int grow = r0 + rt * 16 + q * 4 + r;
          if (grow < n) {
            float v = fmaxf(acc[ct][r] + bias[ct], 0.f);
            bs[ct] += v;
            bq[ct] += v * v;
          }
        }
    }
  }
#pragma unroll
  for (int ct = 0; ct < 4; ++ct) {
    bs[ct] += __shfl_xor(bs[ct], 16); bs[ct] += __shfl_xor(bs[ct], 32);
    bq[ct] += __shfl_xor(bq[ct], 16); bq[ct] += __shfl_xor(bq[ct], 32);
  }
  if (q == 0) {
    int cpy = ((int)blockIdx.x & 3) * 512;
#pragma unroll
    for (int ct = 0; ct < 4; ++ct) {
      int col = colbase + ct * 16 + l16;
      atomicAdd(&bnacc[cpy + col], bs[ct]);
      atomicAdd(&bnacc[cpy + 256 + col], bq[ct]);
    }
  }
}

// ---------------- finalize BN + fold into W2 (bf16 transposed) / b2 ----------------
__global__ __launch_bounds__(256) void k_final(const float* __restrict__ bnacc,
    const float* __restrict__ gamma, const float* __restrict__ beta,
    const float* __restrict__ W2, const float* __restrict__ b2,
    ushort* __restrict__ W2pt, float* __restrict__ b2p, float invN) {
  __shared__ float scb[MIDF], shb[MIDF], red[256];
  int tid = threadIdx.x;
  float s = bnacc[tid] + bnacc[512 + tid] + bnacc[1024 + tid] + bnacc[1536 + tid];
  float qv = bnacc[256 + tid] + bnacc[768 + tid] + bnacc[1280 + tid] + bnacc[1792 + tid];
  float mu = s * invN;
  float var = qv * invN - mu * mu;
  float sc = gamma[tid] * rsqrtf(var + BN_EPS);
  scb[tid] = sc;
  shb[tid] = beta[tid] - mu * sc;
  __syncthreads();
  float sp = 0.f;
  for (int i = tid; i < MIDF * OUTF; i += 256) {
    int k = i >> 6, c = i & 63;
    float wv = W2[i];
    W2pt[(size_t)c * MIDF + k] = f2bf(scb[k] * wv);   // [64 col][256 k] bf16
    sp += shb[k] * wv;
  }
  red[tid] = sp;
  __syncthreads();
  if (tid < 64)
    b2p[tid] = b2[tid] + red[tid] + red[64 + tid] + red[128 + tid] + red[192 + tid];
}

// ---- back end: 16-row tiles; recompute h=relu(agg@W1+b1) into LDS, then @W2pt+b2p -> out ----
__global__ __launch_bounds__(256, 4) void k_back(const ushort* __restrict__ agg,
    const ushort* __restrict__ W1t, const float* __restrict__ b1,
    const ushort* __restrict__ W2pt, const float* __restrict__ b2p,
    float* __restrict__ out, int n, int nt16) {
  __shared__ ushort hT[16 * HT_LD];     // 8448 B
  int tid = threadIdx.x, w = tid >> 6, lane = tid & 63;
  int q = lane >> 4, l16 = lane & 15;
  // wave w: GEMM1 cols [w*64, w*64+64) register-resident
  bf16x8 B1f[4][4];
  float bias1[4];
#pragma unroll
  for (int ct = 0; ct < 4; ++ct) {
    int col = w * 64 + ct * 16 + l16;
#pragma unroll
    for (int ks = 0; ks < 4; ++ks)
      B1f[ct][ks] = *(const bf16x8*)(W1t + (size_t)col * TWO_C + ks * 32 + q * 8);
    bias1[ct] = b1[col];
  }
  float b2b = b2p[w * 16 + l16];
  for (int t = blockIdx.x; t < nt16; t += gridDim.x) {
    int r0 = t * 16;
    int row = r0 + l16;
    bool ok = row < n;
    bf16x8 Af[4];
#pragma unroll
    for (int ks = 0; ks < 4; ++ks) {
      bf16x8 v;
#pragma unroll
      for (int j = 0; j < 8; ++j) v[j] = 0;
      if (ok) v = *(const bf16x8*)(agg + (size_t)row * TWO_C + ks * 32 + q * 8);
      Af[ks] = v;
    }
    f32x4 acc1[4];
#pragma unroll
    for (int ct = 0; ct < 4; ++ct) acc1[ct] = (f32x4){0.f, 0.f, 0.f, 0.f};
#pragma unroll
    for (int ks = 0; ks < 4; ++ks)
#pragma unroll
      for (int ct = 0; ct < 4; ++ct)
        acc1[ct] = __builtin_amdgcn_mfma_f32_16x16x32_bf16(Af[ks], B1f[ct][ks], acc1[ct], 0, 0, 0);
#pragma unroll
    for (int ct = 0; ct < 4; ++ct)
#pragma unroll
      for (int r = 0; r < 4; ++r)
        hT[(q * 4 + r) * HT_LD + w * 64 + ct * 16 + l16] =
            f2bf(fmaxf(acc1[ct][r] + bias1[ct], 0.f));
    __syncthreads();
    // stage 2: wave w -> out cols [w*16, w*16+16), rows r0..r0+15
    f32x4 acc2 = (f32x4){0.f, 0.f, 0.f, 0.f};
#pragma unroll
    for (int ks = 0; ks < 8; ++ks) {
      bf16x8 A2 = *(const bf16x8*)(hT + (size_t)l16 * HT_LD + ks * 32 + q * 8);
      bf16x8 B2 = *(const bf16x8*)(W2pt + (size_t)(w * 16 + l16) * MIDF + ks * 32 + q * 8);
      acc2 = __builtin_amdgcn_mfma_f32_16x16x32_bf16(A2, B2, acc2, 0, 0, 0);
    }
#pragma unroll
    for (int r = 0; r < 4; ++r) {
      int gr = r0 + q * 4 + r;
      if (gr < n) out[(size_t)gr * OUTF + w * 16 + l16] = acc2[r] + b2b;
    }
    __syncthreads();
  }
}

extern "C" void kernel_launch(void* const* d_in, const int* in_sizes, int n_in,
                              void* d_out, int out_size, void* d_ws, size_t ws_size,
                              hipStream_t stream) {
  const float* x     = (const float*)d_in[0];
  const int*   ei    = (const int*)d_in[1];
  const float* ea    = (const float*)d_in[2];
  const float* W1    = (const float*)d_in[4];
  const float* b1    = (const float*)d_in[5];
  const float* gamma = (const float*)d_in[6];
  const float* beta  = (const float*)d_in[7];
  const float* W2    = (const float*)d_in[8];
  const float* b2    = (const float*)d_in[9];
  float* out = (float*)d_out;
  int E = in_sizes[2];
  int n = in_sizes[3];
  int NB = (n + 63) >> 6;               // 64-node buckets (1563 for n=100000)

  // workspace layout
  char* ws = (char*)d_ws;
  ushort* agg  = (ushort*)ws;                          // n*128 bf16 (25.6 MB)
  ushort* xb   = agg + (size_t)n * TWO_C;              // n*64 bf16 (12.8 MB)
  uint2* ebt   = (uint2*)(xb + (size_t)n * CF);        // NBMAX*BCAP recs (13.1 MB)
  ushort* W1t  = (ushort*)(ebt + (size_t)NBMAX * BCAP);// 32768 bf16 (64 KB)
  ushort* W2pt = W1t + TWO_C * MIDF;                   // 16384 bf16 (32 KB)
  float* b2p   = (float*)(W2pt + MIDF * OUTF);         // 64 f32
  int* gcur    = (int*)(b2p + 64);                     // NBMAX int
  float* bnacc = (float*)(gcur + NBMAX);               // 2048 f32 (4 spread copies)

  int nchunks = (E + 4095) / 4096;
  hipLaunchKernelGGL(k_init, dim3(1), dim3(1024), 0, stream, gcur, bnacc, NB);
  hipLaunchKernelGGL(k_front, dim3(nchunks + 257), dim3(1024), 0, stream,
                     ei, ea, gcur, ebt, E, NB, nchunks,
                     (const float4*)x, (uint4*)xb, n * CF / 8, W1, W1t);
  hipLaunchKernelGGL(k_sortagg, dim3(NB), dim3(512), 0, stream, xb, ebt, gcur, agg, n);
  int nt = (n + 63) / 64;
  hipLaunchKernelGGL(k_stats, dim3(1024), dim3(256), 0, stream, agg, W1t, b1, bnacc, n, nt);
  hipLaunchKernelGGL(k_final, dim3(1), dim3(256), 0, stream, bnacc, gamma, beta,
                     W2, b2, W2pt, b2p, 1.0f / (float)n);
  int nt16 = (n + 15) / 16;
  hipLaunchKernelGGL(k_back, dim3(2048), dim3(256), 0, stream,
                     agg, W1t, b1, W2pt, b2p, out, n, nt16);
}

// Round 5
// 258.485 us; speedup vs baseline: 1.7661x; 1.0185x over previous
//
#include <hip/hip_runtime.h>
#include <hip/hip_bf16.h>

#define MIDF 256
#define OUTF 64
#define CF 64
#define TWO_C 128
#define BN_EPS 1e-5f
#define BCAP 1024    // per-64-node-bucket capacity (mean 819, +7 sigma margin)
#define NBMAX 1600
#define GSTR 16      // gcur stride (ints): 1 bucket per 64B cache line (atomic contention fix)

typedef __attribute__((ext_vector_type(8))) short bf16x8;
typedef __attribute__((ext_vector_type(4))) float f32x4;

__device__ __forceinline__ ushort f2bf(float f) {
  union { float f; unsigned u; } v; v.f = f;
  return (ushort)((v.u + 0x7fffu + ((v.u >> 16) & 1u)) >> 16);
}
__device__ __forceinline__ float bf2f(unsigned u16) {
  union { unsigned u; float f; } v; v.u = u16 << 16;
  return v.f;
}

// ---------------- init bucket cursors + bnacc ----------------
__global__ __launch_bounds__(1024) void k_init(int* __restrict__ gcur,
                                               float* __restrict__ bnacc, int NB) {
  int i = threadIdx.x;
  for (; i < NB; i += 1024) gcur[i * GSTR] = i * BCAP;
  i = threadIdx.x;
  if (i < 512) bnacc[i] = 0.f;
}

// ---------------- fused front end: bucket scatter (blocks < nchunks) + x cast ----------------
__global__ __launch_bounds__(1024) void k_front(const int* __restrict__ ei,
    const float* __restrict__ ea, int* __restrict__ gcur, uint2* __restrict__ ebt,
    int E, int NB, int nchunks,
    const float4* __restrict__ xp, uint4* __restrict__ xb, int n8) {
  __shared__ int lh[NBMAX];
  __shared__ int lb[NBMAX];
  int tid = threadIdx.x;
  if ((int)blockIdx.x >= nchunks) {
    // ---- x -> bf16 cast path ----
    int nb2 = gridDim.x - nchunks;
    int i = ((int)blockIdx.x - nchunks) * 1024 + tid;
    int st = nb2 * 1024;
    for (; i < n8; i += st) {
      float4 a = xp[2 * i], b = xp[2 * i + 1];
      uint4 o;
      o.x = (unsigned)f2bf(a.x) | ((unsigned)f2bf(a.y) << 16);
      o.y = (unsigned)f2bf(a.z) | ((unsigned)f2bf(a.w) << 16);
      o.z = (unsigned)f2bf(b.x) | ((unsigned)f2bf(b.y) << 16);
      o.w = (unsigned)f2bf(b.z) | ((unsigned)f2bf(b.w) << 16);
      xb[i] = o;
    }
    return;
  }
  // ---- bucket scatter path: 4096-edge chunk, 16 waves ----
  int c0 = blockIdx.x * 4096;
  for (int b = tid; b < NB; b += 1024) lh[b] = 0;
  __syncthreads();
  int rows[4];
#pragma unroll
  for (int j = 0; j < 4; ++j) {
    int e = c0 + j * 1024 + tid;
    int r = (e < E) ? ei[e] : -1;
    rows[j] = r;
    if (r >= 0) atomicAdd(&lh[r >> 6], 1);
  }
  __syncthreads();
  for (int b = tid; b < NB; b += 1024) {
    int c = lh[b];
    lb[b] = (c > 0) ? atomicAdd(&gcur[b * GSTR], c) : 0;
  }
  __syncthreads();
#pragma unroll
  for (int j = 0; j < 4; ++j) {
    int r = rows[j];
    if (r >= 0) {
      int e = c0 + j * 1024 + tid;
      int pos = atomicAdd(&lb[r >> 6], 1);
      ebt[pos] = make_uint2((unsigned)ei[E + e] | ((unsigned)(r & 63) << 20),
                            __float_as_uint(ea[e]));
    }
  }
}

// ---------------- fused bucket sort (to LDS) + segmented mean ----------------
__global__ __launch_bounds__(512, 4) void k_sortagg(const ushort* __restrict__ xb,
    const uint2* __restrict__ ebt, const int* __restrict__ gcur,
    ushort* __restrict__ agg, int n) {
  __shared__ uint2 recs[BCAP];        // 8 KB sorted records
  __shared__ int hist[64], cbase[64], cursor[64];
  int tid = threadIdx.x;
  int b = blockIdx.x;
  int base = b * BCAP;
  int cnt = gcur[b * GSTR] - base;
  cnt = min(cnt, BCAP);
  if (tid < 64) hist[tid] = 0;
  __syncthreads();
  // single global read of ebt into registers (2 recs/thread)
  uint2 e0 = make_uint2(0u, 0u), e1 = make_uint2(0u, 0u);
  bool v0 = tid < cnt, v1 = 512 + tid < cnt;
  if (v0) e0 = ebt[base + tid];
  if (v1) e1 = ebt[base + 512 + tid];
  if (v0) atomicAdd(&hist[(e0.x >> 20) & 63], 1);
  if (v1) atomicAdd(&hist[(e1.x >> 20) & 63], 1);
  __syncthreads();
  if (tid < 64) {                      // wave 0: 64-wide inclusive scan
    int v = hist[tid];
    int sc = v;
#pragma unroll
    for (int d = 1; d < 64; d <<= 1) {
      int t = __shfl_up(sc, d);
      if (tid >= d) sc += t;
    }
    cbase[tid] = sc - v;
    cursor[tid] = sc - v;
  }
  __syncthreads();
  if (v0) {
    int pos = atomicAdd(&cursor[(e0.x >> 20) & 63], 1);
    recs[pos] = make_uint2(e0.x & 0xFFFFF, e0.y);
  }
  if (v1) {
    int pos = atomicAdd(&cursor[(e1.x >> 20) & 63], 1);
    recs[pos] = make_uint2(e1.x & 0xFFFFF, e1.y);
  }
  __syncthreads();
  int w = tid >> 6, lane = tid & 63;
  int q4 = lane >> 4, l16 = lane & 15;
#pragma unroll
  for (int j = 0; j < 8; ++j) {
    int rl = w * 8 + j;
    int v = (b << 6) + rl;
    if (v >= n) continue;
    int s = cbase[rl], d = hist[rl];
    int e = s + d;
    float s0 = 0.f, s1 = 0.f, s2 = 0.f, s3 = 0.f;
    float t0 = 0.f, t1 = 0.f, t2 = 0.f, t3 = 0.f;
    int i = s + q4;
    for (; i + 4 < e; i += 8) {
      uint2 pa = recs[i], pb = recs[i + 4];
      uint2 xa = *(const uint2*)(xb + (size_t)pa.x * CF + 4 * l16);
      uint2 xc = *(const uint2*)(xb + (size_t)pb.x * CF + 4 * l16);
      float wa = __uint_as_float(pa.y), wb = __uint_as_float(pb.y);
      float a0 = bf2f(xa.x & 0xffff), a1 = bf2f(xa.x >> 16);
      float a2 = bf2f(xa.y & 0xffff), a3 = bf2f(xa.y >> 16);
      float b0 = bf2f(xc.x & 0xffff), b1 = bf2f(xc.x >> 16);
      float b2 = bf2f(xc.y & 0xffff), b3 = bf2f(xc.y >> 16);
      s0 += a0 + b0; s1 += a1 + b1; s2 += a2 + b2; s3 += a3 + b3;
      t0 += a0 * wa + b0 * wb; t1 += a1 * wa + b1 * wb;
      t2 += a2 * wa + b2 * wb; t3 += a3 * wa + b3 * wb;
    }
    if (i < e) {
      uint2 p = recs[i];
      uint2 xv = *(const uint2*)(xb + (size_t)p.x * CF + 4 * l16);
      float wt = __uint_as_float(p.y);
      float a0 = bf2f(xv.x & 0xffff), a1 = bf2f(xv.x >> 16);
      float a2 = bf2f(xv.y & 0xffff), a3 = bf2f(xv.y >> 16);
      s0 += a0; s1 += a1; s2 += a2; s3 += a3;
      t0 += a0 * wt; t1 += a1 * wt; t2 += a2 * wt; t3 += a3 * wt;
    }
    s0 += __shfl_xor(s0, 16); s1 += __shfl_xor(s1, 16);
    s2 += __shfl_xor(s2, 16); s3 += __shfl_xor(s3, 16);
    t0 += __shfl_xor(t0, 16); t1 += __shfl_xor(t1, 16);
    t2 += __shfl_xor(t2, 16); t3 += __shfl_xor(t3, 16);
    s0 += __shfl_xor(s0, 32); s1 += __shfl_xor(s1, 32);
    s2 += __shfl_xor(s2, 32); s3 += __shfl_xor(s3, 32);
    t0 += __shfl_xor(t0, 32); t1 += __shfl_xor(t1, 32);
    t2 += __shfl_xor(t2, 32); t3 += __shfl_xor(t3, 32);
    float inv = 1.0f / fmaxf((float)d, 1.0f);
    if (q4 == 0) {
      uint2 o;
      o.x = (unsigned)f2bf(s0 * inv) | ((unsigned)f2bf(s1 * inv) << 16);
      o.y = (unsigned)f2bf(s2 * inv) | ((unsigned)f2bf(s3 * inv) << 16);
      *(uint2*)(agg + (size_t)v * TWO_C + 4 * l16) = o;
      uint2 p2;
      p2.x = (unsigned)f2bf(t0 * inv) | ((unsigned)f2bf(t1 * inv) << 16);
      p2.y = (unsigned)f2bf(t2 * inv) | ((unsigned)f2bf(t3 * inv) << 16);
      *(uint2*)(agg + (size_t)v * TWO_C + CF + 4 * l16) = p2;
    }
  }
}

// ---------------- GEMM1 (MFMA) + fused BN partial stats ----------------
__global__ __launch_bounds__(256, 3) void k_gemm1(const ushort* __restrict__ agg,
    const float* __restrict__ W1, const float* __restrict__ b1,
    ushort* __restrict__ h, float* __restrict__ bnacc, int n, int ntiles) {
  int tid = threadIdx.x, w = tid >> 6, lane = tid & 63;
  int q = lane >> 4, l16 = lane & 15;
  int cg = blockIdx.x & 3;
  int colbase = cg * 64;
  bf16x8 Bf[4][4];
#pragma unroll
  for (int ct = 0; ct < 4; ++ct)
#pragma unroll
    for (int ks = 0; ks < 4; ++ks) {
      int c = colbase + ct * 16 + l16;
      int k0 = ks * 32 + q * 8;
#pragma unroll
      for (int j = 0; j < 8; ++j)
        Bf[ct][ks][j] = (short)f2bf(W1[(size_t)(k0 + j) * MIDF + c]);
    }
  float bias[4];
#pragma unroll
  for (int ct = 0; ct < 4; ++ct) bias[ct] = b1[colbase + ct * 16 + l16];
  __shared__ ushort tile[64 * 72];
  int c_stat = tid & 63, rb = tid >> 6;
  float s_sum = 0.f, s_sq = 0.f;
  int nb = gridDim.x >> 2;
  for (int t = blockIdx.x >> 2; t < ntiles; t += nb) {
    int r0 = t * 64;
    int myrow = r0 + w * 16 + l16;
    bf16x8 Af[4];
#pragma unroll
    for (int ks = 0; ks < 4; ++ks) {
      bf16x8 av;
#pragma unroll
      for (int j = 0; j < 8; ++j) av[j] = 0;
      if (myrow < n) av = *(const bf16x8*)(agg + (size_t)myrow * TWO_C + ks * 32 + q * 8);
      Af[ks] = av;
    }
    f32x4 acc[4];
#pragma unroll
    for (int ct = 0; ct < 4; ++ct) acc[ct] = (f32x4){0.f, 0.f, 0.f, 0.f};
#pragma unroll
    for (int ks = 0; ks < 4; ++ks)
#pragma unroll
      for (int ct = 0; ct < 4; ++ct)
        acc[ct] = __builtin_amdgcn_mfma_f32_16x16x32_bf16(Af[ks], Bf[ct][ks], acc[ct], 0, 0, 0);
    __syncthreads();
#pragma unroll
    for (int ct = 0; ct < 4; ++ct)
#pragma unroll
      for (int r = 0; r < 4; ++r) {
        float vv = fmaxf(acc[ct][r] + bias[ct], 0.f);
        tile[(w * 16 + q * 4 + r) * 72 + ct * 16 + l16] = f2bf(vv);
      }
    __syncthreads();
    int row = tid >> 2, co = (tid & 3) * 16;
    int gr = r0 + row;
    if (gr < n) {
      const uint4* src = (const uint4*)(tile + row * 72 + co);
      uint4* dst = (uint4*)(h + (size_t)gr * MIDF + colbase + co);
      dst[0] = src[0];
      dst[1] = src[1];
    }
#pragma unroll 4
    for (int r = 0; r < 16; ++r) {
      int rr = rb * 16 + r;
      if (r0 + rr < n) {
        float vv = bf2f(tile[rr * 72 + c_stat]);
        s_sum += vv;
        s_sq += vv * vv;
      }
    }
  }
  __syncthreads();
  float* red = (float*)tile;
  red[rb * 64 + c_stat] = s_sum;
  red[256 + rb * 64 + c_stat] = s_sq;
  __syncthreads();
  if (tid < 128) {
    int c = tid & 63, isq = tid >> 6;
    int base = isq * 256;
    float v = red[base + c] + red[base + 64 + c] + red[base + 128 + c] + red[base + 192 + c];
    atomicAdd(&bnacc[isq * MIDF + colbase + c], v);
  }
}

// ---------------- finalize BN + fold into W2/b2 ----------------
__global__ __launch_bounds__(256) void k_final(const float* __restrict__ bnacc,
    const float* __restrict__ gamma, const float* __restrict__ beta,
    const float* __restrict__ W2, const float* __restrict__ b2,
    float* __restrict__ W2p, float* __restrict__ b2p, float invN) {
  __shared__ float scb[MIDF], shb[MIDF], red[256];
  int tid = threadIdx.x;
  float s = bnacc[tid];
  float q = bnacc[MIDF + tid];
  float mu = s * invN;
  float var = q * invN - mu * mu;
  float sc = gamma[tid] * rsqrtf(var + BN_EPS);
  scb[tid] = sc;
  shb[tid] = beta[tid] - mu * sc;
  __syncthreads();
  float sp = 0.f;
  for (int i = tid; i < MIDF * OUTF; i += 256) {
    int k = i >> 6;
    float wv = W2[i];
    W2p[i] = scb[k] * wv;
    sp += shb[k] * wv;
  }
  red[tid] = sp;
  __syncthreads();
  if (tid < 64)
    b2p[tid] = b2[tid] + red[tid] + red[64 + tid] + red[128 + tid] + red[192 + tid];
}

// ---------------- GEMM2 (MFMA): h[N,256]bf16 @ W2p[256,64] + b2p -> out fp32 ----------------
__global__ __launch_bounds__(256, 2) void k_gemm2(const ushort* __restrict__ h,
    const float* __restrict__ W2p, const float* __restrict__ b2p,
    float* __restrict__ out, int n, int ntiles) {
  int tid = threadIdx.x, w = tid >> 6, lane = tid & 63;
  int q = lane >> 4, l16 = lane & 15;
  bf16x8 Bf[4][8];
#pragma unroll
  for (int ct = 0; ct < 4; ++ct)
#pragma unroll
    for (int ks = 0; ks < 8; ++ks) {
      int c = ct * 16 + l16;
      int k0 = ks * 32 + q * 8;
#pragma unroll
      for (int j = 0; j < 8; ++j)
        Bf[ct][ks][j] = (short)f2bf(W2p[(size_t)(k0 + j) * OUTF + c]);
    }
  float bias[4];
#pragma unroll
  for (int ct = 0; ct < 4; ++ct) bias[ct] = b2p[ct * 16 + l16];
  __shared__ float tile[64 * 68];
  for (int t = blockIdx.x; t < ntiles; t += gridDim.x) {
    int r0 = t * 64;
    int myrow = r0 + w * 16 + l16;
    f32x4 acc[4];
#pragma unroll
    for (int ct = 0; ct < 4; ++ct) acc[ct] = (f32x4){0.f, 0.f, 0.f, 0.f};
#pragma unroll
    for (int ks = 0; ks < 8; ++ks) {
      bf16x8 av;
#pragma unroll
      for (int j = 0; j < 8; ++j) av[j] = 0;
      if (myrow < n) av = *(const bf16x8*)(h + (size_t)myrow * MIDF + ks * 32 + q * 8);
#pragma unroll
      for (int ct = 0; ct < 4; ++ct)
        acc[ct] = __builtin_amdgcn_mfma_f32_16x16x32_bf16(av, Bf[ct][ks], acc[ct], 0, 0, 0);
    }
    __syncthreads();
#pragma unroll
    for (int ct = 0; ct < 4; ++ct)
#pragma unroll
      for (int r = 0; r < 4; ++r)
        tile[(w * 16 + q * 4 + r) * 68 + ct * 16 + l16] = acc[ct][r] + bias[ct];
    __syncthreads();
    int row = tid >> 2, co = (tid & 3) * 16;
    int gr = t * 64 + row;
    if (gr < n) {
      const float4* src = (const float4*)(tile + row * 68 + co);
      float4* dst = (float4*)(out + (size_t)gr * OUTF + co);
      dst[0] = src[0];
      dst[1] = src[1];
      dst[2] = src[2];
      dst[3] = src[3];
    }
  }
}

extern "C" void kernel_launch(void* const* d_in, const int* in_sizes, int n_in,
                              void* d_out, int out_size, void* d_ws, size_t ws_size,
                              hipStream_t stream) {
  const float* x     = (const float*)d_in[0];
  const int*   ei    = (const int*)d_in[1];
  const float* ea    = (const float*)d_in[2];
  const float* W1    = (const float*)d_in[4];
  const float* b1    = (const float*)d_in[5];
  const float* gamma = (const float*)d_in[6];
  const float* beta  = (const float*)d_in[7];
  const float* W2    = (const float*)d_in[8];
  const float* b2    = (const float*)d_in[9];
  float* out = (float*)d_out;
  int E = in_sizes[2];
  int n = in_sizes[3];
  int NB = (n + 63) >> 6;               // 64-node buckets (1563 for n=100000)

  // workspace layout (round-0, with padded gcur)
  char* ws = (char*)d_ws;
  ushort* agg = (ushort*)ws;                          // n*128 bf16
  ushort* h   = agg + (size_t)n * TWO_C;              // n*256 bf16 (51.2 MB)
  ushort* xb  = h + (size_t)n * MIDF;                 // n*64 bf16
  float* W2p  = (float*)(xb + (size_t)n * CF);        // 16384 f32
  float* b2p  = W2p + MIDF * OUTF;                    // 64 f32
  int* gcur   = (int*)(b2p + 64);                     // NBMAX*GSTR int (64B/bucket)
  float* bnacc= (float*)(gcur + NBMAX * GSTR);        // 512 f32 (zeroed by k_init)
  uint2* ebt  = (uint2*)h;                            // NB*BCAP recs (12.8MB, alias in h)

  int nchunks = (E + 4095) / 4096;
  hipLaunchKernelGGL(k_init, dim3(1), dim3(1024), 0, stream, gcur, bnacc, NB);
  hipLaunchKernelGGL(k_front, dim3(nchunks + 256), dim3(1024), 0, stream,
                     ei, ea, gcur, ebt, E, NB, nchunks,
                     (const float4*)x, (uint4*)xb, n * CF / 8);
  hipLaunchKernelGGL(k_sortagg, dim3(NB), dim3(512), 0, stream, xb, ebt, gcur, agg, n);
  int nt = (n + 63) / 64;
  hipLaunchKernelGGL(k_gemm1, dim3(768), dim3(256), 0, stream, agg, W1, b1, h, bnacc, n, nt);
  hipLaunchKernelGGL(k_final, dim3(1), dim3(256), 0, stream, bnacc, gamma, beta,
                     W2, b2, W2p, b2p, 1.0f / (float)n);
  hipLaunchKernelGGL(k_gemm2, dim3(512), dim3(256), 0, stream, h, W2p, b2p, out, n, nt);
}